// Round 16
// baseline (646.317 us; speedup 1.0000x reference)
//
#include <hip/hip_runtime.h>
#include <hip/hip_bf16.h>
#include <math.h>

// B=2, C=128, H=W=64, heads=4, head_dim=32, kernel=7 (49 taps), depth=2.
// Inputs fp32, OUTPUT fp32. Intermediates bf16. MFMA GEMMs.
// R16: ONE persistent kernel, 512 blocks x 256 thr (2 blocks/CU co-resident
// by LDS sizing + __launch_bounds__(256,2)), 5 device-scope grid barriers.
// Phases: P0 prep | P1 qkv0 | P2 attn0 | P3 proj0+qkv1 | P4 attn1 |
// P5 proj1+LN+NCHW-store.
#define PIX 8192
#define RSTRIDE 72
typedef __attribute__((ext_vector_type(8))) short short8;
typedef __attribute__((ext_vector_type(4))) float f32x4;

__device__ inline float bflo(unsigned u) { return __uint_as_float(u << 16); }
__device__ inline float bfhi(unsigned u) { return __uint_as_float(u & 0xffff0000u); }
__device__ inline unsigned short f2b(float f) {
  __hip_bfloat16 h = __float2bfloat16(f);
  return *reinterpret_cast<unsigned short*>(&h);
}
__device__ inline unsigned pack2(float a, float b) {
  return (unsigned)f2b(a) | ((unsigned)f2b(b) << 16);
}

union Smem {
  float ptile[64][129];                                  // P0 transpose (33 KB)
  struct {                                               // P2/P4 attn (55 KB)
    unsigned short kbuf[140 * RSTRIDE];
    unsigned short vbuf[140 * RSTRIDE];
    float rb[338];
    float sc[64][52];
  } at;
  unsigned short po[16 * 136];                           // P3 chain tile (4.3 KB)
  struct { float tile[16][132]; float mean[16]; float rstd[16]; } ln;  // P5
};

// grid-wide barrier: all-thread release fence, tid0 arrive+spin, acquire fence.
__device__ __forceinline__ void gridbar(unsigned* __restrict__ bar, int slot) {
  __threadfence();
  __syncthreads();
  if (threadIdx.x == 0) {
    atomicAdd(&bar[slot], 1u);
    while (atomicAdd(&bar[slot], 0u) < 512u) __builtin_amdgcn_s_sleep(2);
  }
  __syncthreads();
  __threadfence();
}

__device__ __forceinline__ void attn_phase(const unsigned short* __restrict__ qkvp,
                                           const float* __restrict__ rpb,
                                           unsigned short* __restrict__ outp,
                                           int bid, int tid, Smem& sm) {
  int tile = bid & 127;
  int hp = (bid >> 7) & 1;
  int bz = bid >> 8;
  int ti = tile >> 4, tj = tile & 15;       // 8 x 16 tiles of 8x4 px
  int bi0 = ti * 8 - 3, bj0 = tj * 4 - 3;   // halo origin (14 x 10)

  for (int t = tid; t < 338; t += 256) sm.at.rb[t] = rpb[hp * 338 + t];

  for (int t = tid; t < 2240; t += 256) {
    int row = t >> 4;
    int sub = t & 15;
    int isv = sub >> 3;
    int c = sub & 7;
    int ri = row / 10, rj = row - ri * 10;
    int gi = bi0 + ri, gj = bj0 + rj;
    uint4 val = make_uint4(0, 0, 0, 0);
    if ((unsigned)gi < 64u && (unsigned)gj < 64u) {
      int pixn = (bz * 64 + gi) * 64 + gj;
      val = *(const uint4*)(qkvp + (size_t)pixn * 384 + 128 + isv * 128 +
                            hp * 64 + c * 8);
    }
    *(uint4*)((isv ? sm.at.vbuf : sm.at.kbuf) + row * RSTRIDE + c * 8) = val;
  }
  __syncthreads();

  int r = tid & 3;
  int hl = (tid >> 2) & 1;
  int px = tid >> 3;
  int ph = px * 2 + hl;
  int pi = px >> 2, pj = px & 3;
  int i = ti * 8 + pi, j = tj * 4 + pj;
  int si = min(max(i - 3, 0), 57), sj = min(max(j - 3, 0), 57);
  int li = si - bi0, lj = sj - bj0;
  int oi = i - si, oj = j - sj;
  int H = hp * 2 + hl;
  int pix = (bz * 64 + i) * 64 + j;

  const float scale = 0.17677669529663687f;   // 32^-0.5
  float q[8];
  {
    uint4 t = *(const uint4*)(qkvp + (size_t)pix * 384 + H * 32 + r * 8);
    q[0] = bflo(t.x) * scale;  q[1] = bfhi(t.x) * scale;
    q[2] = bflo(t.y) * scale;  q[3] = bfhi(t.y) * scale;
    q[4] = bflo(t.z) * scale;  q[5] = bfhi(t.z) * scale;
    q[6] = bflo(t.w) * scale;  q[7] = bfhi(t.w) * scale;
  }

  const unsigned short* kh = sm.at.kbuf + hl * 32 + r * 8;
  const unsigned short* vh = sm.at.vbuf + hl * 32 + r * 8;
  const float* rbh = sm.at.rb + hl * 169;

#pragma unroll
  for (int p = 0; p < 7; ++p) {
#pragma unroll
    for (int qq = 0; qq < 7; ++qq) {
      int n = (li + p) * 10 + (lj + qq);
      uint4 t = *(const uint4*)(kh + n * RSTRIDE);
      float dot = q[0] * bflo(t.x) + q[1] * bfhi(t.x)
                + q[2] * bflo(t.y) + q[3] * bfhi(t.y)
                + q[4] * bflo(t.z) + q[5] * bfhi(t.z)
                + q[6] * bflo(t.w) + q[7] * bfhi(t.w);
      dot += __shfl_xor(dot, 1);
      dot += __shfl_xor(dot, 2);
      if (r == 0)
        sm.at.sc[ph][p * 7 + qq] = dot + rbh[(p + 6 - oi) * 13 + (qq + 6 - oj)];
    }
  }
  __syncthreads();

  float m = -INFINITY;
#pragma unroll
  for (int n = 0; n < 49; ++n) m = fmaxf(m, sm.at.sc[ph][n]);

  float sum = 0.f;
  float acc[8] = {0.f, 0.f, 0.f, 0.f, 0.f, 0.f, 0.f, 0.f};
#pragma unroll
  for (int p = 0; p < 7; ++p) {
#pragma unroll
    for (int qq = 0; qq < 7; ++qq) {
      float e = __expf(sm.at.sc[ph][p * 7 + qq] - m);
      sum += e;
      int n = (li + p) * 10 + (lj + qq);
      uint4 t = *(const uint4*)(vh + n * RSTRIDE);
      acc[0] += e * bflo(t.x);  acc[1] += e * bfhi(t.x);
      acc[2] += e * bflo(t.y);  acc[3] += e * bfhi(t.y);
      acc[4] += e * bflo(t.z);  acc[5] += e * bfhi(t.z);
      acc[6] += e * bflo(t.w);  acc[7] += e * bfhi(t.w);
    }
  }
  float inv = 1.f / sum;
  uint4 t;
  t.x = pack2(acc[0] * inv, acc[1] * inv);
  t.y = pack2(acc[2] * inv, acc[3] * inv);
  t.z = pack2(acc[4] * inv, acc[5] * inv);
  t.w = pack2(acc[6] * inv, acc[7] * inv);
  *(uint4*)(outp + (size_t)pix * 128 + H * 32 + r * 8) = t;
}

__global__ __launch_bounds__(256, 2) void mega(
    const float* __restrict__ x, const float* __restrict__ qw,
    const float* __restrict__ qb, const float* __restrict__ rpb,
    const float* __restrict__ pw, const float* __restrict__ pb,
    const float* __restrict__ lg, const float* __restrict__ lb,
    unsigned short* __restrict__ ya, unsigned short* __restrict__ qkv,
    unsigned short* __restrict__ wq, unsigned short* __restrict__ wp,
    unsigned* __restrict__ bar, float* __restrict__ out) {
  __shared__ Smem sm;
  int bid = blockIdx.x;
  int tid = threadIdx.x;
  int w = tid >> 6, lane = tid & 63;
  int quad = lane >> 4, l16 = lane & 15;

  // ---- P0: prep (transpose + weight cvt) ----
  if (bid < 128) {
    int b = bid >> 6, i = bid & 63;
    const float* xbase = x + (size_t)b * 128 * 4096 + (size_t)i * 64;
    for (int idx = tid; idx < 8192; idx += 256) {
      int c = idx >> 6, j = idx & 63;
      sm.ptile[j][c] = xbase[(size_t)c * 4096 + j];
    }
    __syncthreads();
    unsigned short* yrow = ya + (size_t)bid * 64 * 128;
    for (int idx = tid; idx < 8192; idx += 256) {
      int j = idx >> 7, c = idx & 127;
      yrow[idx] = f2b(sm.ptile[j][c]);
    }
  } else {
    int idx = (bid - 128) * 256 + tid;       // 384 blocks -> 98304
    if (idx < 98304) wq[idx] = f2b(qw[idx]);
    if (idx < 32768) wp[idx] = f2b(pw[idx]);
  }
  gridbar(bar, 0);

  // ---- P1: qkv0 GEMM (16 px/block; wave w -> cols [96w, 96w+96)) ----
  {
    int m0 = bid * 16;
    const short8* ap = (const short8*)(ya + (size_t)(m0 + l16) * 128 + quad * 8);
    short8 a[4];
#pragma unroll
    for (int kc = 0; kc < 4; ++kc) a[kc] = ap[kc * 4];
#pragma unroll
    for (int nt = 0; nt < 6; ++nt) {
      int col = w * 96 + nt * 16 + l16;
      const short8* bp = (const short8*)(wq + (size_t)col * 128 + quad * 8);
      f32x4 c = {0.f, 0.f, 0.f, 0.f};
#pragma unroll
      for (int kc = 0; kc < 4; ++kc)
        c = __builtin_amdgcn_mfma_f32_16x16x32_bf16(a[kc], bp[kc * 4], c, 0, 0, 0);
      float bv = qb[col];
#pragma unroll
      for (int r2 = 0; r2 < 4; ++r2)
        qkv[(size_t)(m0 + quad * 4 + r2) * 384 + col] = f2b(c[r2] + bv);
    }
  }
  gridbar(bar, 1);

  // ---- P2: attn layer 0 (reads qkv, writes ya) ----
  attn_phase(qkv, rpb, ya, bid, tid, sm);
  gridbar(bar, 2);

  // ---- P3: proj0 + qkv1, LDS-chained (16 px/block) ----
  {
    int m0 = bid * 16;
    const short8* ap = (const short8*)(ya + (size_t)(m0 + l16) * 128 + quad * 8);
    short8 a[4];
#pragma unroll
    for (int kc = 0; kc < 4; ++kc) a[kc] = ap[kc * 4];
#pragma unroll
    for (int nt = 0; nt < 2; ++nt) {         // proj: wave w cols [32w,32w+32)
      int col = w * 32 + nt * 16 + l16;
      const short8* bp = (const short8*)(wp + (size_t)col * 128 + quad * 8);
      f32x4 c = {0.f, 0.f, 0.f, 0.f};
#pragma unroll
      for (int kc = 0; kc < 4; ++kc)
        c = __builtin_amdgcn_mfma_f32_16x16x32_bf16(a[kc], bp[kc * 4], c, 0, 0, 0);
      float bv = pb[col];
#pragma unroll
      for (int r2 = 0; r2 < 4; ++r2)
        sm.po[(quad * 4 + r2) * 136 + col] = f2b(c[r2] + bv);
    }
    __syncthreads();
    short8 a2[4];
#pragma unroll
    for (int kc = 0; kc < 4; ++kc)
      a2[kc] = *(const short8*)(sm.po + l16 * 136 + kc * 32 + quad * 8);
#pragma unroll
    for (int nt = 0; nt < 6; ++nt) {         // qkv1: wave w cols [96w,96w+96)
      int col = w * 96 + nt * 16 + l16;
      const short8* bp = (const short8*)(wq + 49152 + (size_t)col * 128 + quad * 8);
      f32x4 c = {0.f, 0.f, 0.f, 0.f};
#pragma unroll
      for (int kc = 0; kc < 4; ++kc)
        c = __builtin_amdgcn_mfma_f32_16x16x32_bf16(a2[kc], bp[kc * 4], c, 0, 0, 0);
      float bv = qb[384 + col];
#pragma unroll
      for (int r2 = 0; r2 < 4; ++r2)
        qkv[(size_t)(m0 + quad * 4 + r2) * 384 + col] = f2b(c[r2] + bv);
    }
  }
  gridbar(bar, 3);

  // ---- P4: attn layer 1 ----
  attn_phase(qkv, rpb + 676, ya, bid, tid, sm);
  gridbar(bar, 4);

  // ---- P5: proj1 + LayerNorm + NCHW store (16 px/block) ----
  {
    int m0 = bid * 16;
    const short8* ap = (const short8*)(ya + (size_t)(m0 + l16) * 128 + quad * 8);
    short8 a[4];
#pragma unroll
    for (int kc = 0; kc < 4; ++kc) a[kc] = ap[kc * 4];
#pragma unroll
    for (int nt = 0; nt < 2; ++nt) {
      int col = w * 32 + nt * 16 + l16;
      const short8* bp = (const short8*)(wp + 16384 + (size_t)col * 128 + quad * 8);
      f32x4 c = {0.f, 0.f, 0.f, 0.f};
#pragma unroll
      for (int kc = 0; kc < 4; ++kc)
        c = __builtin_amdgcn_mfma_f32_16x16x32_bf16(a[kc], bp[kc * 4], c, 0, 0, 0);
      float bv = pb[128 + col];
#pragma unroll
      for (int r2 = 0; r2 < 4; ++r2)
        sm.ln.tile[quad * 4 + r2][col] = c[r2] + bv;
    }
    __syncthreads();
    int pxl = tid >> 4, li16 = tid & 15;     // 16 threads per pixel
    float s = 0.f, s2 = 0.f;
#pragma unroll
    for (int cc = 0; cc < 8; ++cc) {
      float v = sm.ln.tile[pxl][li16 * 8 + cc];
      s += v; s2 += v * v;
    }
    s += __shfl_xor(s, 1);  s += __shfl_xor(s, 2);
    s += __shfl_xor(s, 4);  s += __shfl_xor(s, 8);
    s2 += __shfl_xor(s2, 1);  s2 += __shfl_xor(s2, 2);
    s2 += __shfl_xor(s2, 4);  s2 += __shfl_xor(s2, 8);
    if (li16 == 0) {
      float mu = s * (1.f / 128.f);
      sm.ln.mean[pxl] = mu;
      sm.ln.rstd[pxl] = rsqrtf(s2 * (1.f / 128.f) - mu * mu + 1e-5f);
    }
    __syncthreads();
    int b = m0 >> 12, i = (m0 >> 6) & 63, j0 = m0 & 63;
    int jloc = tid & 15, chi = tid >> 4;
#pragma unroll
    for (int k = 0; k < 8; ++k) {
      int c = chi + 16 * k;
      float v = (sm.ln.tile[jloc][c] - sm.ln.mean[jloc]) * sm.ln.rstd[jloc]
                * lg[c] + lb[c];
      out[(((size_t)b * 128 + c) * 64 + i) * 64 + j0 + jloc] = v;
    }
  }
}

extern "C" void kernel_launch(void* const* d_in, const int* in_sizes, int n_in,
                              void* d_out, int out_size, void* d_ws, size_t ws_size,
                              hipStream_t stream) {
  (void)in_sizes; (void)n_in; (void)out_size; (void)ws_size;
  const float* x   = (const float*)d_in[0];
  const float* qw  = (const float*)d_in[1];   // (2,384,128)
  const float* qb  = (const float*)d_in[2];   // (2,384)
  const float* rpb = (const float*)d_in[3];   // (2,4,13,13)
  const float* pw  = (const float*)d_in[4];   // (2,128,128)
  const float* pb  = (const float*)d_in[5];   // (2,128)
  const float* lg  = (const float*)d_in[6];
  const float* lb  = (const float*)d_in[7];

  unsigned short* ya   = (unsigned short*)d_ws;          // y0/attn (2 MB)
  unsigned short* qkv  = ya + (size_t)PIX * 128;         // PIX*384 (6 MB)
  unsigned short* wq   = qkv + (size_t)PIX * 384;        // 98304
  unsigned short* wp   = wq + 98304;                     // 32768
  unsigned* bar = (unsigned*)(wp + 32768);               // 5 barrier slots
  float* out = (float*)d_out;

  hipMemsetAsync(bar, 0, 64, stream);
  mega<<<512, 256, 0, stream>>>(x, qw, qb, rpb, pw, pb, lg, lb,
                                ya, qkv, wq, wp, bar, out);
}

// Round 17
// 645.418 us; speedup vs baseline: 1.0014x; 1.0014x over previous
//
#include <hip/hip_runtime.h>
#include <hip/hip_bf16.h>
#include <math.h>

// B=2, C=128, H=W=64, heads=4, head_dim=32, kernel=7 (49 taps), depth=2.
// Inputs fp32, OUTPUT fp32. Intermediates bf16. MFMA GEMMs.
// R17 = R16 persistent kernel with a LOAD-SPIN grid barrier (R16's
// atomicAdd(p,0) RMW-spin cost ~120us/barrier; coherent load spin doesn't
// ping-pong the line). Phases unchanged: P0 prep | P1 qkv0 | P2 attn0 |
// P3 proj0+qkv1 | P4 attn1 | P5 proj1+LN+NCHW-store.
#define PIX 8192
#define RSTRIDE 72
typedef __attribute__((ext_vector_type(8))) short short8;
typedef __attribute__((ext_vector_type(4))) float f32x4;

__device__ inline float bflo(unsigned u) { return __uint_as_float(u << 16); }
__device__ inline float bfhi(unsigned u) { return __uint_as_float(u & 0xffff0000u); }
__device__ inline unsigned short f2b(float f) {
  __hip_bfloat16 h = __float2bfloat16(f);
  return *reinterpret_cast<unsigned short*>(&h);
}
__device__ inline unsigned pack2(float a, float b) {
  return (unsigned)f2b(a) | ((unsigned)f2b(b) << 16);
}

union Smem {
  float ptile[64][129];                                  // P0 transpose (33 KB)
  struct {                                               // P2/P4 attn (55 KB)
    unsigned short kbuf[140 * RSTRIDE];
    unsigned short vbuf[140 * RSTRIDE];
    float rb[338];
    float sc[64][52];
  } at;
  unsigned short po[16 * 136];                           // P3 chain tile (4.3 KB)
  struct { float tile[16][132]; float mean[16]; float rstd[16]; } ln;  // P5
};

// grid barrier: all-thread release fence, tid0 arrive (one RMW) + LOAD-spin,
// all-thread acquire fence. Validated fencing structure from R16.
__device__ __forceinline__ void gridbar(unsigned* __restrict__ bar, int slot) {
  __threadfence();
  __syncthreads();
  if (threadIdx.x == 0) {
    atomicAdd(&bar[slot], 1u);
    while (__hip_atomic_load(&bar[slot], __ATOMIC_RELAXED,
                             __HIP_MEMORY_SCOPE_AGENT) < 512u)
      __builtin_amdgcn_s_sleep(8);
  }
  __syncthreads();
  __threadfence();
}

__device__ __forceinline__ void attn_phase(const unsigned short* __restrict__ qkvp,
                                           const float* __restrict__ rpb,
                                           unsigned short* __restrict__ outp,
                                           int bid, int tid, Smem& sm) {
  int tile = bid & 127;
  int hp = (bid >> 7) & 1;
  int bz = bid >> 8;
  int ti = tile >> 4, tj = tile & 15;       // 8 x 16 tiles of 8x4 px
  int bi0 = ti * 8 - 3, bj0 = tj * 4 - 3;   // halo origin (14 x 10)

  for (int t = tid; t < 338; t += 256) sm.at.rb[t] = rpb[hp * 338 + t];

  for (int t = tid; t < 2240; t += 256) {
    int row = t >> 4;
    int sub = t & 15;
    int isv = sub >> 3;
    int c = sub & 7;
    int ri = row / 10, rj = row - ri * 10;
    int gi = bi0 + ri, gj = bj0 + rj;
    uint4 val = make_uint4(0, 0, 0, 0);
    if ((unsigned)gi < 64u && (unsigned)gj < 64u) {
      int pixn = (bz * 64 + gi) * 64 + gj;
      val = *(const uint4*)(qkvp + (size_t)pixn * 384 + 128 + isv * 128 +
                            hp * 64 + c * 8);
    }
    *(uint4*)((isv ? sm.at.vbuf : sm.at.kbuf) + row * RSTRIDE + c * 8) = val;
  }
  __syncthreads();

  int r = tid & 3;
  int hl = (tid >> 2) & 1;
  int px = tid >> 3;
  int ph = px * 2 + hl;
  int pi = px >> 2, pj = px & 3;
  int i = ti * 8 + pi, j = tj * 4 + pj;
  int si = min(max(i - 3, 0), 57), sj = min(max(j - 3, 0), 57);
  int li = si - bi0, lj = sj - bj0;
  int oi = i - si, oj = j - sj;
  int H = hp * 2 + hl;
  int pix = (bz * 64 + i) * 64 + j;

  const float scale = 0.17677669529663687f;   // 32^-0.5
  float q[8];
  {
    uint4 t = *(const uint4*)(qkvp + (size_t)pix * 384 + H * 32 + r * 8);
    q[0] = bflo(t.x) * scale;  q[1] = bfhi(t.x) * scale;
    q[2] = bflo(t.y) * scale;  q[3] = bfhi(t.y) * scale;
    q[4] = bflo(t.z) * scale;  q[5] = bfhi(t.z) * scale;
    q[6] = bflo(t.w) * scale;  q[7] = bfhi(t.w) * scale;
  }

  const unsigned short* kh = sm.at.kbuf + hl * 32 + r * 8;
  const unsigned short* vh = sm.at.vbuf + hl * 32 + r * 8;
  const float* rbh = sm.at.rb + hl * 169;

#pragma unroll
  for (int p = 0; p < 7; ++p) {
#pragma unroll
    for (int qq = 0; qq < 7; ++qq) {
      int n = (li + p) * 10 + (lj + qq);
      uint4 t = *(const uint4*)(kh + n * RSTRIDE);
      float dot = q[0] * bflo(t.x) + q[1] * bfhi(t.x)
                + q[2] * bflo(t.y) + q[3] * bfhi(t.y)
                + q[4] * bflo(t.z) + q[5] * bfhi(t.z)
                + q[6] * bflo(t.w) + q[7] * bfhi(t.w);
      dot += __shfl_xor(dot, 1);
      dot += __shfl_xor(dot, 2);
      if (r == 0)
        sm.at.sc[ph][p * 7 + qq] = dot + rbh[(p + 6 - oi) * 13 + (qq + 6 - oj)];
    }
  }
  __syncthreads();

  float m = -INFINITY;
#pragma unroll
  for (int n = 0; n < 49; ++n) m = fmaxf(m, sm.at.sc[ph][n]);

  float sum = 0.f;
  float acc[8] = {0.f, 0.f, 0.f, 0.f, 0.f, 0.f, 0.f, 0.f};
#pragma unroll
  for (int p = 0; p < 7; ++p) {
#pragma unroll
    for (int qq = 0; qq < 7; ++qq) {
      float e = __expf(sm.at.sc[ph][p * 7 + qq] - m);
      sum += e;
      int n = (li + p) * 10 + (lj + qq);
      uint4 t = *(const uint4*)(vh + n * RSTRIDE);
      acc[0] += e * bflo(t.x);  acc[1] += e * bfhi(t.x);
      acc[2] += e * bflo(t.y);  acc[3] += e * bfhi(t.y);
      acc[4] += e * bflo(t.z);  acc[5] += e * bfhi(t.z);
      acc[6] += e * bflo(t.w);  acc[7] += e * bfhi(t.w);
    }
  }
  float inv = 1.f / sum;
  uint4 t;
  t.x = pack2(acc[0] * inv, acc[1] * inv);
  t.y = pack2(acc[2] * inv, acc[3] * inv);
  t.z = pack2(acc[4] * inv, acc[5] * inv);
  t.w = pack2(acc[6] * inv, acc[7] * inv);
  *(uint4*)(outp + (size_t)pix * 128 + H * 32 + r * 8) = t;
}

__global__ __launch_bounds__(256, 2) void mega(
    const float* __restrict__ x, const float* __restrict__ qw,
    const float* __restrict__ qb, const float* __restrict__ rpb,
    const float* __restrict__ pw, const float* __restrict__ pb,
    const float* __restrict__ lg, const float* __restrict__ lb,
    unsigned short* __restrict__ ya, unsigned short* __restrict__ qkv,
    unsigned short* __restrict__ wq, unsigned short* __restrict__ wp,
    unsigned* __restrict__ bar, float* __restrict__ out) {
  __shared__ Smem sm;
  int bid = blockIdx.x;
  int tid = threadIdx.x;
  int w = tid >> 6, lane = tid & 63;
  int quad = lane >> 4, l16 = lane & 15;

  // ---- P0: prep (transpose + weight cvt) ----
  if (bid < 128) {
    int b = bid >> 6, i = bid & 63;
    const float* xbase = x + (size_t)b * 128 * 4096 + (size_t)i * 64;
    for (int idx = tid; idx < 8192; idx += 256) {
      int c = idx >> 6, j = idx & 63;
      sm.ptile[j][c] = xbase[(size_t)c * 4096 + j];
    }
    __syncthreads();
    unsigned short* yrow = ya + (size_t)bid * 64 * 128;
    for (int idx = tid; idx < 8192; idx += 256) {
      int j = idx >> 7, c = idx & 127;
      yrow[idx] = f2b(sm.ptile[j][c]);
    }
  } else {
    int idx = (bid - 128) * 256 + tid;       // 384 blocks -> 98304
    if (idx < 98304) wq[idx] = f2b(qw[idx]);
    if (idx < 32768) wp[idx] = f2b(pw[idx]);
  }
  gridbar(bar, 0);

  // ---- P1: qkv0 GEMM (16 px/block; wave w -> cols [96w, 96w+96)) ----
  {
    int m0 = bid * 16;
    const short8* ap = (const short8*)(ya + (size_t)(m0 + l16) * 128 + quad * 8);
    short8 a[4];
#pragma unroll
    for (int kc = 0; kc < 4; ++kc) a[kc] = ap[kc * 4];
#pragma unroll
    for (int nt = 0; nt < 6; ++nt) {
      int col = w * 96 + nt * 16 + l16;
      const short8* bp = (const short8*)(wq + (size_t)col * 128 + quad * 8);
      f32x4 c = {0.f, 0.f, 0.f, 0.f};
#pragma unroll
      for (int kc = 0; kc < 4; ++kc)
        c = __builtin_amdgcn_mfma_f32_16x16x32_bf16(a[kc], bp[kc * 4], c, 0, 0, 0);
      float bv = qb[col];
#pragma unroll
      for (int r2 = 0; r2 < 4; ++r2)
        qkv[(size_t)(m0 + quad * 4 + r2) * 384 + col] = f2b(c[r2] + bv);
    }
  }
  gridbar(bar, 1);

  // ---- P2: attn layer 0 (reads qkv, writes ya) ----
  attn_phase(qkv, rpb, ya, bid, tid, sm);
  gridbar(bar, 2);

  // ---- P3: proj0 + qkv1, LDS-chained (16 px/block) ----
  {
    int m0 = bid * 16;
    const short8* ap = (const short8*)(ya + (size_t)(m0 + l16) * 128 + quad * 8);
    short8 a[4];
#pragma unroll
    for (int kc = 0; kc < 4; ++kc) a[kc] = ap[kc * 4];
#pragma unroll
    for (int nt = 0; nt < 2; ++nt) {         // proj: wave w cols [32w,32w+32)
      int col = w * 32 + nt * 16 + l16;
      const short8* bp = (const short8*)(wp + (size_t)col * 128 + quad * 8);
      f32x4 c = {0.f, 0.f, 0.f, 0.f};
#pragma unroll
      for (int kc = 0; kc < 4; ++kc)
        c = __builtin_amdgcn_mfma_f32_16x16x32_bf16(a[kc], bp[kc * 4], c, 0, 0, 0);
      float bv = pb[col];
#pragma unroll
      for (int r2 = 0; r2 < 4; ++r2)
        sm.po[(quad * 4 + r2) * 136 + col] = f2b(c[r2] + bv);
    }
    __syncthreads();
    short8 a2[4];
#pragma unroll
    for (int kc = 0; kc < 4; ++kc)
      a2[kc] = *(const short8*)(sm.po + l16 * 136 + kc * 32 + quad * 8);
#pragma unroll
    for (int nt = 0; nt < 6; ++nt) {         // qkv1: wave w cols [96w,96w+96)
      int col = w * 96 + nt * 16 + l16;
      const short8* bp = (const short8*)(wq + 49152 + (size_t)col * 128 + quad * 8);
      f32x4 c = {0.f, 0.f, 0.f, 0.f};
#pragma unroll
      for (int kc = 0; kc < 4; ++kc)
        c = __builtin_amdgcn_mfma_f32_16x16x32_bf16(a2[kc], bp[kc * 4], c, 0, 0, 0);
      float bv = qb[384 + col];
#pragma unroll
      for (int r2 = 0; r2 < 4; ++r2)
        qkv[(size_t)(m0 + quad * 4 + r2) * 384 + col] = f2b(c[r2] + bv);
    }
  }
  gridbar(bar, 3);

  // ---- P4: attn layer 1 ----
  attn_phase(qkv, rpb + 676, ya, bid, tid, sm);
  gridbar(bar, 4);

  // ---- P5: proj1 + LayerNorm + NCHW store (16 px/block) ----
  {
    int m0 = bid * 16;
    const short8* ap = (const short8*)(ya + (size_t)(m0 + l16) * 128 + quad * 8);
    short8 a[4];
#pragma unroll
    for (int kc = 0; kc < 4; ++kc) a[kc] = ap[kc * 4];
#pragma unroll
    for (int nt = 0; nt < 2; ++nt) {
      int col = w * 32 + nt * 16 + l16;
      const short8* bp = (const short8*)(wp + 16384 + (size_t)col * 128 + quad * 8);
      f32x4 c = {0.f, 0.f, 0.f, 0.f};
#pragma unroll
      for (int kc = 0; kc < 4; ++kc)
        c = __builtin_amdgcn_mfma_f32_16x16x32_bf16(a[kc], bp[kc * 4], c, 0, 0, 0);
      float bv = pb[128 + col];
#pragma unroll
      for (int r2 = 0; r2 < 4; ++r2)
        sm.ln.tile[quad * 4 + r2][col] = c[r2] + bv;
    }
    __syncthreads();
    int pxl = tid >> 4, li16 = tid & 15;     // 16 threads per pixel
    float s = 0.f, s2 = 0.f;
#pragma unroll
    for (int cc = 0; cc < 8; ++cc) {
      float v = sm.ln.tile[pxl][li16 * 8 + cc];
      s += v; s2 += v * v;
    }
    s += __shfl_xor(s, 1);  s += __shfl_xor(s, 2);
    s += __shfl_xor(s, 4);  s += __shfl_xor(s, 8);
    s2 += __shfl_xor(s2, 1);  s2 += __shfl_xor(s2, 2);
    s2 += __shfl_xor(s2, 4);  s2 += __shfl_xor(s2, 8);
    if (li16 == 0) {
      float mu = s * (1.f / 128.f);
      sm.ln.mean[pxl] = mu;
      sm.ln.rstd[pxl] = rsqrtf(s2 * (1.f / 128.f) - mu * mu + 1e-5f);
    }
    __syncthreads();
    int b = m0 >> 12, i = (m0 >> 6) & 63, j0 = m0 & 63;
    int jloc = tid & 15, chi = tid >> 4;
#pragma unroll
    for (int k = 0; k < 8; ++k) {
      int c = chi + 16 * k;
      float v = (sm.ln.tile[jloc][c] - sm.ln.mean[jloc]) * sm.ln.rstd[jloc]
                * lg[c] + lb[c];
      out[(((size_t)b * 128 + c) * 64 + i) * 64 + j0 + jloc] = v;
    }
  }
}

extern "C" void kernel_launch(void* const* d_in, const int* in_sizes, int n_in,
                              void* d_out, int out_size, void* d_ws, size_t ws_size,
                              hipStream_t stream) {
  (void)in_sizes; (void)n_in; (void)out_size; (void)ws_size;
  const float* x   = (const float*)d_in[0];
  const float* qw  = (const float*)d_in[1];   // (2,384,128)
  const float* qb  = (const float*)d_in[2];   // (2,384)
  const float* rpb = (const float*)d_in[3];   // (2,4,13,13)
  const float* pw  = (const float*)d_in[4];   // (2,128,128)
  const float* pb  = (const float*)d_in[5];   // (2,128)
  const float* lg  = (const float*)d_in[6];
  const float* lb  = (const float*)d_in[7];

  unsigned short* ya   = (unsigned short*)d_ws;          // y0/attn (2 MB)
  unsigned short* qkv  = ya + (size_t)PIX * 128;         // PIX*384 (6 MB)
  unsigned short* wq   = qkv + (size_t)PIX * 384;        // 98304
  unsigned short* wp   = wq + 98304;                     // 32768
  unsigned* bar = (unsigned*)(wp + 32768);               // 5 barrier slots
  float* out = (float*)d_out;

  hipMemsetAsync(bar, 0, 64, stream);
  mega<<<512, 256, 0, stream>>>(x, qw, qb, rpb, pw, pb, lg, lb,
                                ya, qkv, wq, wp, bar, out);
}

// Round 18
// 146.566 us; speedup vs baseline: 4.4097x; 4.4036x over previous
//
#include <hip/hip_runtime.h>
#include <hip/hip_bf16.h>
#include <math.h>

// B=2, C=128, H=W=64, heads=4, head_dim=32, kernel=7 (49 taps), depth=2.
// Inputs fp32, OUTPUT fp32. Intermediates bf16. MFMA GEMMs.
// R18 = R14 (best: 146.6us) with input-transpose fused into qkv0:
//   cvtw | xqkv (x->qkv0, LDS transpose + MFMA) | attn0 | proj0 | qkv1 |
//   attn1 | proj1 | ln_out.   Persistent-kernel path (R16/R17) abandoned:
//   grid barriers cost ~100us each regardless of spin style (fence-bound).
#define PIX 8192
typedef __hip_bfloat16 bf16;
typedef __attribute__((ext_vector_type(8))) short short8;
typedef __attribute__((ext_vector_type(4))) float f32x4;

__device__ inline float bflo(unsigned u) { return __uint_as_float(u << 16); }
__device__ inline float bfhi(unsigned u) { return __uint_as_float(u & 0xffff0000u); }
__device__ inline unsigned short f2b(float f) {
  __hip_bfloat16 h = __float2bfloat16(f);
  return *reinterpret_cast<unsigned short*>(&h);
}
__device__ inline unsigned pack2(float a, float b) {
  return (unsigned)f2b(a) | ((unsigned)f2b(b) << 16);
}

// ---------- weight conversion fp32 -> bf16 ----------
__global__ __launch_bounds__(256) void cvtw(const float* __restrict__ qw,
                                            const float* __restrict__ pw,
                                            unsigned short* __restrict__ wq,
                                            unsigned short* __restrict__ wp) {
  int idx = blockIdx.x * 256 + threadIdx.x;   // 384 blocks -> 98304
  if (idx < 98304) wq[idx] = f2b(qw[idx]);
  if (idx < 32768) wp[idx] = f2b(pw[idx]);
}

// ---------- fused transpose + qkv0: x (NCHW fp32) -> qkv (bf16) ----------
// 512 blocks x 16 px. Stage 16x128 bf16 A-tile in LDS (stride 136), then
// R16-P1 wave layout: wave w -> cols [96w, 96w+96), A-frag row = lane&15.
__global__ __launch_bounds__(256) void xqkv(const float* __restrict__ x,
                                            const unsigned short* __restrict__ wq,
                                            const float* __restrict__ qb,
                                            unsigned short* __restrict__ qkv) {
  __shared__ __align__(16) unsigned short As[16 * 136];
  int m0 = blockIdx.x * 16;
  int tid = threadIdx.x;
  int b = m0 >> 12, i = (m0 >> 6) & 63, j0 = m0 & 63;

  for (int idx = tid; idx < 2048; idx += 256) {
    int c = idx >> 4, jl = idx & 15;
    As[jl * 136 + c] =
        f2b(x[(size_t)b * 524288 + (size_t)c * 4096 + i * 64 + j0 + jl]);
  }
  __syncthreads();

  int w = tid >> 6, lane = tid & 63;
  int quad = lane >> 4, l16 = lane & 15;
  short8 a[4];
#pragma unroll
  for (int kc = 0; kc < 4; ++kc)
    a[kc] = *(const short8*)(As + l16 * 136 + kc * 32 + quad * 8);
#pragma unroll
  for (int nt = 0; nt < 6; ++nt) {
    int col = w * 96 + nt * 16 + l16;
    const short8* bp = (const short8*)(wq + (size_t)col * 128 + quad * 8);
    f32x4 c = {0.f, 0.f, 0.f, 0.f};
#pragma unroll
    for (int kc = 0; kc < 4; ++kc)
      c = __builtin_amdgcn_mfma_f32_16x16x32_bf16(a[kc], bp[kc * 4], c, 0, 0, 0);
    float bv = qb[col];
#pragma unroll
    for (int r2 = 0; r2 < 4; ++r2)
      qkv[(size_t)(m0 + quad * 4 + r2) * 384 + col] = f2b(c[r2] + bv);
  }
}

// ---------- MFMA GEMM: C[M,N] = A[M,128] * W[N,128]^T + bias ----------
__global__ __launch_bounds__(256) void gemm_mfma(const unsigned short* __restrict__ A,
                                                 const unsigned short* __restrict__ W,
                                                 const float* __restrict__ bias,
                                                 unsigned short* __restrict__ Cmat,
                                                 int N) {
  int m0 = blockIdx.x * 64, n0 = blockIdx.y * 64;
  int tid = threadIdx.x;
  int w = tid >> 6, lane = tid & 63;
  int quad = lane >> 4, l16 = lane & 15;

  const short8* ap =
      (const short8*)(A + (size_t)(m0 + w * 16 + l16) * 128 + quad * 8);
  short8 a[4];
#pragma unroll
  for (int kc = 0; kc < 4; ++kc) a[kc] = ap[kc * 4];

  f32x4 acc[4];
#pragma unroll
  for (int nt = 0; nt < 4; ++nt) {
    const short8* bp =
        (const short8*)(W + (size_t)(n0 + nt * 16 + l16) * 128 + quad * 8);
    f32x4 c = {0.f, 0.f, 0.f, 0.f};
#pragma unroll
    for (int kc = 0; kc < 4; ++kc)
      c = __builtin_amdgcn_mfma_f32_16x16x32_bf16(a[kc], bp[kc * 4], c, 0, 0, 0);
    acc[nt] = c;
  }

#pragma unroll
  for (int nt = 0; nt < 4; ++nt) {
    int col = n0 + nt * 16 + l16;
    float bv = bias[col];
#pragma unroll
    for (int r = 0; r < 4; ++r) {
      int m = m0 + w * 16 + quad * 4 + r;
      Cmat[(size_t)m * N + col] = f2b(acc[nt][r] + bv);
    }
  }
}

// ---------- neighborhood attention v6 (unchanged from R14) ----------
#define RSTRIDE 72
__global__ __launch_bounds__(256, 2) void na_attn(const unsigned short* __restrict__ qkvp,
                                                  const float* __restrict__ rpb,
                                                  unsigned short* __restrict__ out) {
  __shared__ __align__(16) unsigned short kbuf[140 * RSTRIDE];
  __shared__ __align__(16) unsigned short vbuf[140 * RSTRIDE];
  __shared__ float rb[338];
  __shared__ float sc[64][52];

  int ti = blockIdx.x >> 4, tj = blockIdx.x & 15;   // 8 x 16 tiles of 8x4 px
  int hp = blockIdx.y;
  int bz = blockIdx.z;
  int tid = threadIdx.x;
  int bi0 = ti * 8 - 3, bj0 = tj * 4 - 3;           // halo origin

  for (int t = tid; t < 338; t += 256) rb[t] = rpb[hp * 338 + t];

  for (int t = tid; t < 2240; t += 256) {
    int row = t >> 4;            // 0..139
    int sub = t & 15;
    int isv = sub >> 3;          // 0=K, 1=V
    int c = sub & 7;
    int ri = row / 10, rj = row - ri * 10;
    int gi = bi0 + ri, gj = bj0 + rj;
    uint4 val = make_uint4(0, 0, 0, 0);
    if ((unsigned)gi < 64u && (unsigned)gj < 64u) {
      int pixn = (bz * 64 + gi) * 64 + gj;
      val = *(const uint4*)(qkvp + (size_t)pixn * 384 + 128 + isv * 128 +
                            hp * 64 + c * 8);
    }
    *(uint4*)((isv ? vbuf : kbuf) + row * RSTRIDE + c * 8) = val;
  }
  __syncthreads();

  int r = tid & 3;
  int hl = (tid >> 2) & 1;
  int px = tid >> 3;
  int ph = px * 2 + hl;
  int pi = px >> 2, pj = px & 3;
  int i = ti * 8 + pi, j = tj * 4 + pj;
  int si = min(max(i - 3, 0), 57), sj = min(max(j - 3, 0), 57);
  int li = si - bi0, lj = sj - bj0;
  int oi = i - si, oj = j - sj;
  int H = hp * 2 + hl;
  int pix = (bz * 64 + i) * 64 + j;

  const float scale = 0.17677669529663687f;   // 32^-0.5
  float q[8];
  {
    uint4 t = *(const uint4*)(qkvp + (size_t)pix * 384 + H * 32 + r * 8);
    q[0] = bflo(t.x) * scale;  q[1] = bfhi(t.x) * scale;
    q[2] = bflo(t.y) * scale;  q[3] = bfhi(t.y) * scale;
    q[4] = bflo(t.z) * scale;  q[5] = bfhi(t.z) * scale;
    q[6] = bflo(t.w) * scale;  q[7] = bfhi(t.w) * scale;
  }

  const unsigned short* kh = kbuf + hl * 32 + r * 8;
  const unsigned short* vh = vbuf + hl * 32 + r * 8;
  const float* rbh = rb + hl * 169;

#pragma unroll
  for (int p = 0; p < 7; ++p) {
#pragma unroll
    for (int qq = 0; qq < 7; ++qq) {
      int n = (li + p) * 10 + (lj + qq);
      uint4 t = *(const uint4*)(kh + n * RSTRIDE);
      float dot = q[0] * bflo(t.x) + q[1] * bfhi(t.x)
                + q[2] * bflo(t.y) + q[3] * bfhi(t.y)
                + q[4] * bflo(t.z) + q[5] * bfhi(t.z)
                + q[6] * bflo(t.w) + q[7] * bfhi(t.w);
      dot += __shfl_xor(dot, 1);
      dot += __shfl_xor(dot, 2);
      if (r == 0) sc[ph][p * 7 + qq] = dot + rbh[(p + 6 - oi) * 13 + (qq + 6 - oj)];
    }
  }
  __syncthreads();

  float m = -INFINITY;
#pragma unroll
  for (int n = 0; n < 49; ++n) m = fmaxf(m, sc[ph][n]);

  float sum = 0.f;
  float acc[8] = {0.f, 0.f, 0.f, 0.f, 0.f, 0.f, 0.f, 0.f};
#pragma unroll
  for (int p = 0; p < 7; ++p) {
#pragma unroll
    for (int qq = 0; qq < 7; ++qq) {
      float e = __expf(sc[ph][p * 7 + qq] - m);
      sum += e;
      int n = (li + p) * 10 + (lj + qq);
      uint4 t = *(const uint4*)(vh + n * RSTRIDE);
      acc[0] += e * bflo(t.x);  acc[1] += e * bfhi(t.x);
      acc[2] += e * bflo(t.y);  acc[3] += e * bfhi(t.y);
      acc[4] += e * bflo(t.z);  acc[5] += e * bfhi(t.z);
      acc[6] += e * bflo(t.w);  acc[7] += e * bfhi(t.w);
    }
  }
  float inv = 1.f / sum;
  uint4 t;
  t.x = pack2(acc[0] * inv, acc[1] * inv);
  t.y = pack2(acc[2] * inv, acc[3] * inv);
  t.z = pack2(acc[4] * inv, acc[5] * inv);
  t.w = pack2(acc[6] * inv, acc[7] * inv);
  *(uint4*)(out + (size_t)pix * 128 + H * 32 + r * 8) = t;
}

// ---------- LayerNorm over C + transpose to (B,C,H,W), fp32 store ----------
__global__ __launch_bounds__(256) void ln_out(const unsigned short* __restrict__ y,
                                              const float* __restrict__ g,
                                              const float* __restrict__ bta,
                                              float* __restrict__ out) {
  __shared__ float tile[64][129];
  __shared__ float mean_s[64], rstd_s[64];
  int blk = blockIdx.x;
  int b = blk >> 6, i = blk & 63;
  int tid = threadIdx.x;
  const unsigned short* yrow = y + (size_t)blk * 64 * 128;
  for (int idx = tid; idx < 8192; idx += 256) {
    int j = idx >> 7, c = idx & 127;
    tile[j][c] = __uint_as_float((unsigned)yrow[idx] << 16);
  }
  __syncthreads();
  int jj = tid >> 2, qtr = tid & 3;
  float sum = 0.f, sumsq = 0.f;
#pragma unroll
  for (int cc = 0; cc < 32; ++cc) {
    float v = tile[jj][qtr * 32 + cc];
    sum += v; sumsq += v * v;
  }
  sum += __shfl_xor(sum, 1);  sum += __shfl_xor(sum, 2);
  sumsq += __shfl_xor(sumsq, 1);  sumsq += __shfl_xor(sumsq, 2);
  if (qtr == 0) {
    float mu = sum * (1.f / 128.f);
    mean_s[jj] = mu;
    rstd_s[jj] = rsqrtf(sumsq * (1.f / 128.f) - mu * mu + 1e-5f);
  }
  __syncthreads();
  int c0 = tid >> 6;
  int j = tid & 63;
  for (int c = c0; c < 128; c += 4) {
    float v = (tile[j][c] - mean_s[j]) * rstd_s[j] * g[c] + bta[c];
    out[(((size_t)b * 128 + c) * 64 + i) * 64 + j] = v;
  }
}

extern "C" void kernel_launch(void* const* d_in, const int* in_sizes, int n_in,
                              void* d_out, int out_size, void* d_ws, size_t ws_size,
                              hipStream_t stream) {
  (void)in_sizes; (void)n_in; (void)out_size; (void)ws_size;
  const float* x   = (const float*)d_in[0];
  const float* qw  = (const float*)d_in[1];   // (2,384,128)
  const float* qb  = (const float*)d_in[2];   // (2,384)
  const float* rpb = (const float*)d_in[3];   // (2,4,13,13)
  const float* pw  = (const float*)d_in[4];   // (2,128,128)
  const float* pb  = (const float*)d_in[5];   // (2,128)
  const float* lg  = (const float*)d_in[6];
  const float* lb  = (const float*)d_in[7];

  unsigned short* y    = (unsigned short*)d_ws;          // proj outputs (2 MB)
  unsigned short* qkv  = y + (size_t)PIX * 128;          // PIX*384 (6 MB)
  unsigned short* wq   = qkv + (size_t)PIX * 384;        // 98304
  unsigned short* wp   = wq + 98304;                     // 32768
  unsigned short* attn = (unsigned short*)d_out;         // PIX*128 (scratch)
  float* out = (float*)d_out;

  cvtw<<<384, 256, 0, stream>>>(qw, pw, wq, wp);
  xqkv<<<512, 256, 0, stream>>>(x, wq, qb, qkv);                          // qkv0
  na_attn<<<dim3(128, 2, 2), 256, 0, stream>>>(qkv, rpb, attn);           // attn0
  gemm_mfma<<<dim3(128, 2), 256, 0, stream>>>(attn, wp, pb, y, 128);      // proj0
  gemm_mfma<<<dim3(128, 6), 256, 0, stream>>>(y, wq + 49152, qb + 384, qkv, 384); // qkv1
  na_attn<<<dim3(128, 2, 2), 256, 0, stream>>>(qkv, rpb + 676, attn);     // attn1
  gemm_mfma<<<dim3(128, 2), 256, 0, stream>>>(attn, wp + 16384, pb + 128, y, 128); // proj1
  ln_out<<<128, 256, 0, stream>>>(y, lg, lb, out);
}